// Round 2
// baseline (453.574 us; speedup 1.0000x reference)
//
#include <hip/hip_runtime.h>
#include <stdint.h>

// CausalSelfAttention: B=4 T=2048 C=1024 H=16 D=64
// Pipeline: cast->bf16 | GEMM1 (QKV) | flash-attn | GEMM2 (proj, f32 out)

#define SEQ 2048
#define NBATCH 4
#define CEMB 1024
#define NHEAD 16
#define DHEAD 64
#define BTROWS (NBATCH * SEQ)  // 8192

typedef __bf16 bf16x8 __attribute__((ext_vector_type(8)));
typedef float f32x4 __attribute__((ext_vector_type(4)));
typedef uint32_t u32x4 __attribute__((ext_vector_type(4)));
typedef unsigned short u16;

__device__ __forceinline__ u16 f2bf(float f) {
  union { float f; uint32_t u; } x; x.f = f;
  uint32_t u = x.u;
  return (u16)((u + 0x7FFFu + ((u >> 16) & 1u)) >> 16);  // RNE
}

__device__ __forceinline__ void gload_lds16(const void* g, void* l) {
  __builtin_amdgcn_global_load_lds(
      (const __attribute__((address_space(1))) uint32_t*)g,
      (__attribute__((address_space(3))) uint32_t*)l, 16, 0, 0);
}

// ---------------- f32 -> bf16 cast ----------------
__global__ __launch_bounds__(256) void cvt_f32_bf16_kernel(
    const float* __restrict__ in, u16* __restrict__ out, int n4) {
  int i = blockIdx.x * blockDim.x + threadIdx.x;
  int stride = gridDim.x * blockDim.x;
  for (; i < n4; i += stride) {
    float4 v = reinterpret_cast<const float4*>(in)[i];
    ushort4 o;
    o.x = f2bf(v.x); o.y = f2bf(v.y); o.z = f2bf(v.z); o.w = f2bf(v.w);
    reinterpret_cast<ushort4*>(out)[i] = o;
  }
}

// ---------------- GEMM: C[M,N] = A[M,K] * Bt[N,K]^T + bias ----------------
// m97 structure: 128x128 tile, BK=64, 256 thr (2x2 waves, 64x64 each),
// global_load_lds width 16, 16x16x32 bf16 MFMA.
template <bool OUT_BF16>
__global__ __launch_bounds__(256) void gemm_bt_kernel(
    const u16* __restrict__ A, const u16* __restrict__ Bt,
    const float* __restrict__ bias, void* __restrict__ Cout,
    int M, int N, int K) {
  __shared__ u16 As[128][64];  // 16 KB
  __shared__ u16 Bs[128][64];  // 16 KB
  const int tid = threadIdx.x;
  const int lane = tid & 63;
  const int wave = tid >> 6;
  const int wr = wave >> 1, wc = wave & 1;
  const int m0 = blockIdx.y * 128;
  const int n0 = blockIdx.x * 128;
  const int l15 = lane & 15, lhi = lane >> 4;

  f32x4 acc[4][4];
#pragma unroll
  for (int i = 0; i < 4; i++)
#pragma unroll
    for (int j = 0; j < 4; j++) acc[i][j] = (f32x4){0.f, 0.f, 0.f, 0.f};

  const int srow = lane >> 3;       // 0..7
  const int scol = (lane & 7) * 8;  // element col offset (16B units)

  for (int kt = 0; kt < K; kt += 64) {
#pragma unroll
    for (int i = 0; i < 4; i++) {
      int rr = (wave * 4 + i) * 8 + srow;
      gload_lds16(A + (size_t)(m0 + rr) * K + kt + scol, &As[(wave * 4 + i) * 8][0]);
      gload_lds16(Bt + (size_t)(n0 + rr) * K + kt + scol, &Bs[(wave * 4 + i) * 8][0]);
    }
    __syncthreads();
#pragma unroll
    for (int ks = 0; ks < 2; ks++) {
      bf16x8 af[4], bfr[4];
#pragma unroll
      for (int mi = 0; mi < 4; mi++)
        af[mi] = *(const bf16x8*)&As[wr * 64 + mi * 16 + l15][ks * 32 + lhi * 8];
#pragma unroll
      for (int ni = 0; ni < 4; ni++)
        bfr[ni] = *(const bf16x8*)&Bs[wc * 64 + ni * 16 + l15][ks * 32 + lhi * 8];
#pragma unroll
      for (int mi = 0; mi < 4; mi++)
#pragma unroll
        for (int ni = 0; ni < 4; ni++)
          acc[mi][ni] = __builtin_amdgcn_mfma_f32_16x16x32_bf16(
              af[mi], bfr[ni], acc[mi][ni], 0, 0, 0);
    }
    __syncthreads();
  }

#pragma unroll
  for (int mi = 0; mi < 4; mi++) {
#pragma unroll
    for (int ni = 0; ni < 4; ni++) {
      int n = n0 + wc * 64 + ni * 16 + l15;
      float bv = bias[n];
#pragma unroll
      for (int r = 0; r < 4; r++) {
        int m = m0 + wr * 64 + mi * 16 + lhi * 4 + r;
        float v = acc[mi][ni][r] + bv;
        if constexpr (OUT_BF16)
          ((u16*)Cout)[(size_t)m * N + n] = f2bf(v);
        else
          ((float*)Cout)[(size_t)m * N + n] = v;
      }
    }
  }
}

// ---------------- flash attention ----------------
// grid (32 qtiles, 64 bh), 256 thr. Wave w owns q rows q0+16w..+15.
// qkv layout: [8192 rows][3072] bf16, q|k|v at col offsets 0|1024|2048,
// head h at +h*64. Output Yatt [8192][1024] bf16.
__global__ __launch_bounds__(256) void attn_kernel(
    const u16* __restrict__ qkv, u16* __restrict__ yatt) {
  __shared__ u16 Ks[64][64];   // K chunk, XOR-swizzled 16B blocks, 8 KB
  __shared__ u16 Vt[64][72];   // V^T chunk [d][key], padded, 9 KB
  __shared__ u16 Ps[4][16][72];  // per-wave P, padded, 9 KB

  const int tid = threadIdx.x;
  const int lane = tid & 63;
  const int wave = tid >> 6;
  const int qt = (int)gridDim.x - 1 - (int)blockIdx.x;  // heavy blocks first
  const int bh = blockIdx.y;
  const int b = bh >> 4, h = bh & 15;
  const int l15 = lane & 15, lhi = lane >> 4;

  const size_t rs = 3 * CEMB;  // 3072
  const u16* qb = qkv + (size_t)b * SEQ * rs + h * DHEAD;
  const u16* kb = qb + CEMB;
  const u16* vb = qb + 2 * CEMB;

  const int q0 = qt * 64;

  // Q fragments (A-operand): row = l15, k = dc*32 + lhi*8 + j
  bf16x8 qf[2];
  {
    const u16* qp = qb + (size_t)(q0 + wave * 16 + l15) * rs + lhi * 8;
    qf[0] = *(const bf16x8*)qp;
    qf[1] = *(const bf16x8*)(qp + 32);
  }

  float m_r[4], l_r[4];
  f32x4 o_acc[4];
#pragma unroll
  for (int r = 0; r < 4; r++) { m_r[r] = -1e30f; l_r[r] = 0.f; }
#pragma unroll
  for (int dc = 0; dc < 4; dc++) o_acc[dc] = (f32x4){0.f, 0.f, 0.f, 0.f};

  const float L2E = 1.44269504088896f;
  const float SCL = 0.125f;  // 1/sqrt(64)

  for (int s0 = 0; s0 <= q0; s0 += 64) {
    // stage K via global_load_lds, pre-swizzled source (m173 pattern):
    // LDS(row, cb) holds global(row, cb ^ (row&7))
#pragma unroll
    for (int i = 0; i < 4; i++) {
      int krow = (wave * 4 + i) * 8 + (lane >> 3);
      int cb = (lane & 7) ^ (krow & 7);
      gload_lds16(kb + (size_t)(s0 + krow) * rs + cb * 8, &Ks[(wave * 4 + i) * 8][0]);
    }
    // stage V transposed (reg-staged): lane=key -> conflict-free column writes
    {
      const u16* gv = vb + (size_t)(s0 + lane) * rs + wave * 16;
      union { u32x4 q[2]; u16 u[16]; } tv;
      tv.q[0] = *(const u32x4*)gv;
      tv.q[1] = *(const u32x4*)(gv + 8);
#pragma unroll
      for (int j = 0; j < 16; j++) Vt[wave * 16 + j][lane] = tv.u[j];
    }
    __syncthreads();

    // S = Q K^T : per key-chunk kc, C-frag S[row=q][col=key]
    f32x4 sf[4];
#pragma unroll
    for (int kc = 0; kc < 4; kc++) {
      f32x4 s = (f32x4){0.f, 0.f, 0.f, 0.f};
      int key = kc * 16 + l15;
#pragma unroll
      for (int dc2 = 0; dc2 < 2; dc2++) {
        int cb = (dc2 * 4 + lhi) ^ (key & 7);
        const bf16x8 kf = *(const bf16x8*)((const u16*)&Ks[key][0] + cb * 8);
        s = __builtin_amdgcn_mfma_f32_16x16x32_bf16(qf[dc2], kf, s, 0, 0, 0);
      }
      sf[kc] = s;
    }

    const bool diag = (s0 == q0);
#pragma unroll
    for (int r = 0; r < 4; r++) {
      float sv[4];
      float cmax = -1e30f;
#pragma unroll
      for (int kc = 0; kc < 4; kc++) {
        float s = sf[kc][r] * SCL;
        if (diag && (kc * 16 + l15 > wave * 16 + lhi * 4 + r)) s = -1e30f;
        sv[kc] = s;
        cmax = fmaxf(cmax, s);
      }
#pragma unroll
      for (int msk = 1; msk < 16; msk <<= 1)
        cmax = fmaxf(cmax, __shfl_xor(cmax, msk, 64));
      float mnew = fmaxf(m_r[r], cmax);
      float scf = __builtin_amdgcn_exp2f((m_r[r] - mnew) * L2E);
      m_r[r] = mnew;
      float ps = 0.f;
#pragma unroll
      for (int kc = 0; kc < 4; kc++) {
        float p = __builtin_amdgcn_exp2f((sv[kc] - mnew) * L2E);
        ps += p;
        Ps[wave][lhi * 4 + r][kc * 16 + l15] = f2bf(p);
      }
#pragma unroll
      for (int msk = 1; msk < 16; msk <<= 1) ps += __shfl_xor(ps, msk, 64);
      l_r[r] = l_r[r] * scf + ps;
#pragma unroll
      for (int dc = 0; dc < 4; dc++) o_acc[dc][r] *= scf;
    }

    // PV: A = P (from per-wave LDS), B = V^T rows (contiguous in key)
    bf16x8 pf0 = *(const bf16x8*)&Ps[wave][l15][lhi * 8];
    bf16x8 pf1 = *(const bf16x8*)&Ps[wave][l15][32 + lhi * 8];
#pragma unroll
    for (int dc = 0; dc < 4; dc++) {
      bf16x8 vf0 = *(const bf16x8*)&Vt[dc * 16 + l15][lhi * 8];
      bf16x8 vf1 = *(const bf16x8*)&Vt[dc * 16 + l15][32 + lhi * 8];
      o_acc[dc] = __builtin_amdgcn_mfma_f32_16x16x32_bf16(pf0, vf0, o_acc[dc], 0, 0, 0);
      o_acc[dc] = __builtin_amdgcn_mfma_f32_16x16x32_bf16(pf1, vf1, o_acc[dc], 0, 0, 0);
    }
    __syncthreads();
  }

  // epilogue: O /= l, write [b*T+t][h*64+d] bf16
#pragma unroll
  for (int dc = 0; dc < 4; dc++) {
#pragma unroll
    for (int r = 0; r < 4; r++) {
      int t = q0 + wave * 16 + lhi * 4 + r;
      float o = o_acc[dc][r] / l_r[r];
      yatt[((size_t)(b * SEQ + t)) * CEMB + h * DHEAD + dc * 16 + l15] = f2bf(o);
    }
  }
}

// ---------------- launch ----------------
extern "C" void kernel_launch(void* const* d_in, const int* in_sizes, int n_in,
                              void* d_out, int out_size, void* d_ws, size_t ws_size,
                              hipStream_t stream) {
  const float* x      = (const float*)d_in[0];
  const float* W_attn = (const float*)d_in[1];
  const float* b_attn = (const float*)d_in[2];
  const float* W_proj = (const float*)d_in[3];
  const float* b_proj = (const float*)d_in[4];
  float* out = (float*)d_out;

  u16* Xb   = (u16*)d_ws;                       // 8192*1024
  u16* Wab  = Xb  + (size_t)BTROWS * CEMB;      // 3072*1024
  u16* Wpb  = Wab + (size_t)3 * CEMB * CEMB;    // 1024*1024
  u16* QKV  = Wpb + (size_t)CEMB * CEMB;        // 8192*3072
  u16* Yatt = QKV + (size_t)BTROWS * 3 * CEMB;  // 8192*1024
  // total ws: 92.3 MB

  cvt_f32_bf16_kernel<<<2048, 256, 0, stream>>>(x, Xb, BTROWS * CEMB / 4);
  cvt_f32_bf16_kernel<<<1024, 256, 0, stream>>>(W_attn, Wab, 3 * CEMB * CEMB / 4);
  cvt_f32_bf16_kernel<<<512, 256, 0, stream>>>(W_proj, Wpb, CEMB * CEMB / 4);

  gemm_bt_kernel<true><<<dim3(3 * CEMB / 128, BTROWS / 128), 256, 0, stream>>>(
      Xb, Wab, b_attn, QKV, BTROWS, 3 * CEMB, CEMB);

  attn_kernel<<<dim3(SEQ / 64, NBATCH * NHEAD), 256, 0, stream>>>(QKV, Yatt);

  gemm_bt_kernel<false><<<dim3(CEMB / 128, BTROWS / 128), 256, 0, stream>>>(
      Yatt, Wpb, b_proj, out, BTROWS, CEMB, CEMB);
}

// Round 3
// 383.910 us; speedup vs baseline: 1.1815x; 1.1815x over previous
//
#include <hip/hip_runtime.h>
#include <stdint.h>

// CausalSelfAttention: B=4 T=2048 C=1024 H=16 D=64
// Pipeline: cast->bf16 | GEMM1 (QKV) | flash-attn (swapped-QK^T softmax) | GEMM2

#define SEQ 2048
#define NBATCH 4
#define CEMB 1024
#define NHEAD 16
#define DHEAD 64
#define BTROWS (NBATCH * SEQ)  // 8192

typedef __bf16 bf16x8 __attribute__((ext_vector_type(8)));
typedef float f32x4 __attribute__((ext_vector_type(4)));
typedef uint32_t u32x4 __attribute__((ext_vector_type(4)));
typedef unsigned short u16;

__device__ __forceinline__ u16 f2bf(float f) {
  union { float f; uint32_t u; } x; x.f = f;
  uint32_t u = x.u;
  return (u16)((u + 0x7FFFu + ((u >> 16) & 1u)) >> 16);  // RNE
}

__device__ __forceinline__ void gload_lds16(const void* g, void* l) {
  __builtin_amdgcn_global_load_lds(
      (const __attribute__((address_space(1))) uint32_t*)g,
      (__attribute__((address_space(3))) uint32_t*)l, 16, 0, 0);
}

// ---------------- f32 -> bf16 cast ----------------
__global__ __launch_bounds__(256) void cvt_f32_bf16_kernel(
    const float* __restrict__ in, u16* __restrict__ out, int n4) {
  int i = blockIdx.x * blockDim.x + threadIdx.x;
  int stride = gridDim.x * blockDim.x;
  for (; i < n4; i += stride) {
    float4 v = reinterpret_cast<const float4*>(in)[i];
    ushort4 o;
    o.x = f2bf(v.x); o.y = f2bf(v.y); o.z = f2bf(v.z); o.w = f2bf(v.w);
    reinterpret_cast<ushort4*>(out)[i] = o;
  }
}

// ---------------- GEMM: C[M,N] = A[M,K] * Bt[N,K]^T + bias ----------------
// m97 structure: 128x128 tile, BK=64, 256 thr (2x2 waves, 64x64 each),
// global_load_lds width 16, 16x16x32 bf16 MFMA.
template <bool OUT_BF16>
__global__ __launch_bounds__(256) void gemm_bt_kernel(
    const u16* __restrict__ A, const u16* __restrict__ Bt,
    const float* __restrict__ bias, void* __restrict__ Cout,
    int M, int N, int K) {
  __shared__ u16 As[128][64];  // 16 KB
  __shared__ u16 Bs[128][64];  // 16 KB
  const int tid = threadIdx.x;
  const int lane = tid & 63;
  const int wave = tid >> 6;
  const int wr = wave >> 1, wc = wave & 1;
  const int m0 = blockIdx.y * 128;
  const int n0 = blockIdx.x * 128;
  const int l15 = lane & 15, lhi = lane >> 4;

  f32x4 acc[4][4];
#pragma unroll
  for (int i = 0; i < 4; i++)
#pragma unroll
    for (int j = 0; j < 4; j++) acc[i][j] = (f32x4){0.f, 0.f, 0.f, 0.f};

  const int srow = lane >> 3;       // 0..7
  const int scol = (lane & 7) * 8;  // element col offset (16B units)

  for (int kt = 0; kt < K; kt += 64) {
#pragma unroll
    for (int i = 0; i < 4; i++) {
      int rr = (wave * 4 + i) * 8 + srow;
      gload_lds16(A + (size_t)(m0 + rr) * K + kt + scol, &As[(wave * 4 + i) * 8][0]);
      gload_lds16(Bt + (size_t)(n0 + rr) * K + kt + scol, &Bs[(wave * 4 + i) * 8][0]);
    }
    __syncthreads();
#pragma unroll
    for (int ks = 0; ks < 2; ks++) {
      bf16x8 af[4], bfr[4];
#pragma unroll
      for (int mi = 0; mi < 4; mi++)
        af[mi] = *(const bf16x8*)&As[wr * 64 + mi * 16 + l15][ks * 32 + lhi * 8];
#pragma unroll
      for (int ni = 0; ni < 4; ni++)
        bfr[ni] = *(const bf16x8*)&Bs[wc * 64 + ni * 16 + l15][ks * 32 + lhi * 8];
#pragma unroll
      for (int mi = 0; mi < 4; mi++)
#pragma unroll
        for (int ni = 0; ni < 4; ni++)
          acc[mi][ni] = __builtin_amdgcn_mfma_f32_16x16x32_bf16(
              af[mi], bfr[ni], acc[mi][ni], 0, 0, 0);
    }
    __syncthreads();
  }

#pragma unroll
  for (int mi = 0; mi < 4; mi++) {
#pragma unroll
    for (int ni = 0; ni < 4; ni++) {
      int n = n0 + wc * 64 + ni * 16 + l15;
      float bv = bias[n];
#pragma unroll
      for (int r = 0; r < 4; r++) {
        int m = m0 + wr * 64 + mi * 16 + lhi * 4 + r;
        float v = acc[mi][ni][r] + bv;
        if constexpr (OUT_BF16)
          ((u16*)Cout)[(size_t)m * N + n] = f2bf(v);
        else
          ((float*)Cout)[(size_t)m * N + n] = v;
      }
    }
  }
}

// ---------------- flash attention ----------------
// grid (32 qtiles, 64 bh), 256 thr. Wave w owns q rows q0+16w..+15.
// Swapped QK^T: St = mfma(K_frag, Q_frag) -> lane holds 16 scores for
// ONE q-row (q = lane&15), keys = kc*16 + lhi*4 + r. Softmax reduce is
// 15 in-lane ops + 2 shfl_xor, all 16 q-rows in parallel.
__global__ __launch_bounds__(256) void attn_kernel(
    const u16* __restrict__ qkv, u16* __restrict__ yatt) {
  __shared__ u16 Ks[64][64];     // K chunk, XOR-swizzled 16B blocks, 8 KB
  __shared__ u16 Vt[64][72];     // V^T chunk [d][key], padded, 9 KB
  __shared__ u16 Ps[4][16][72];  // per-wave P [q][key], padded, 9 KB

  const int tid = threadIdx.x;
  const int lane = tid & 63;
  const int wave = tid >> 6;
  const int qt = (int)gridDim.x - 1 - (int)blockIdx.x;  // heavy blocks first
  const int bh = blockIdx.y;
  const int b = bh >> 4, h = bh & 15;
  const int l15 = lane & 15, lhi = lane >> 4;

  const size_t rs = 3 * CEMB;  // 3072
  const u16* qb = qkv + (size_t)b * SEQ * rs + h * DHEAD;
  const u16* kb = qb + CEMB;
  const u16* vb = qb + 2 * CEMB;

  const int q0 = qt * 64;

  // Q fragments (B-operand now): col = l15 = q, k = dc2*32 + lhi*8 + j
  bf16x8 qf[2];
  {
    const u16* qp = qb + (size_t)(q0 + wave * 16 + l15) * rs + lhi * 8;
    qf[0] = *(const bf16x8*)qp;
    qf[1] = *(const bf16x8*)(qp + 32);
  }

  float m_acc = -1e30f, l_acc = 0.f;  // per-lane state for q = l15
  f32x4 o_acc[4];                     // O frag: row lhi*4+r = q, col l15 = d
#pragma unroll
  for (int dc = 0; dc < 4; dc++) o_acc[dc] = (f32x4){0.f, 0.f, 0.f, 0.f};

  const float L2E = 1.44269504088896f;
  const float SCL = 0.125f;  // 1/sqrt(64)

  for (int s0 = 0; s0 <= q0; s0 += 64) {
    // stage K via global_load_lds, pre-swizzled source (m173 pattern):
    // LDS(row, cb) holds global(row, cb ^ (row&7))
#pragma unroll
    for (int i = 0; i < 4; i++) {
      int krow = (wave * 4 + i) * 8 + (lane >> 3);
      int cb = (lane & 7) ^ (krow & 7);
      gload_lds16(kb + (size_t)(s0 + krow) * rs + cb * 8, &Ks[(wave * 4 + i) * 8][0]);
    }
    // stage V transposed (reg-staged): lane=key -> conflict-free column writes
    {
      const u16* gv = vb + (size_t)(s0 + lane) * rs + wave * 16;
      union { u32x4 q[2]; u16 u[16]; } tv;
      tv.q[0] = *(const u32x4*)gv;
      tv.q[1] = *(const u32x4*)(gv + 8);
#pragma unroll
      for (int j = 0; j < 16; j++) Vt[wave * 16 + j][lane] = tv.u[j];
    }
    __syncthreads();

    // St = K Q^T : per key-chunk kc, C-frag St[row=key][col=q]
    f32x4 sf[4];
#pragma unroll
    for (int kc = 0; kc < 4; kc++) {
      f32x4 s = (f32x4){0.f, 0.f, 0.f, 0.f};
      int key = kc * 16 + l15;  // A-frag row = l15 = key
#pragma unroll
      for (int dc2 = 0; dc2 < 2; dc2++) {
        int cb = (dc2 * 4 + lhi) ^ (key & 7);
        const bf16x8 kf = *(const bf16x8*)((const u16*)&Ks[key][0] + cb * 8);
        s = __builtin_amdgcn_mfma_f32_16x16x32_bf16(kf, qf[dc2], s, 0, 0, 0);
      }
      sf[kc] = s;
    }

    // ---- parallel online softmax: lane owns q = l15; keys kc*16+lhi*4+r ----
    const bool diag = (s0 == q0);
    float cmax = -1e30f;
#pragma unroll
    for (int kc = 0; kc < 4; kc++) {
#pragma unroll
      for (int r = 0; r < 4; r++) {
        float s = sf[kc][r] * SCL;
        if (diag && (kc * 16 + lhi * 4 + r > wave * 16 + l15)) s = -1e30f;
        sf[kc][r] = s;
        cmax = fmaxf(cmax, s);
      }
    }
    cmax = fmaxf(cmax, __shfl_xor(cmax, 16, 64));
    cmax = fmaxf(cmax, __shfl_xor(cmax, 32, 64));
    float mnew = fmaxf(m_acc, cmax);
    float scf = __builtin_amdgcn_exp2f((m_acc - mnew) * L2E);
    m_acc = mnew;

    float ps = 0.f;
#pragma unroll
    for (int kc = 0; kc < 4; kc++) {
      union { u16 h[4]; uint2 v; } pw;
#pragma unroll
      for (int r = 0; r < 4; r++) {
        float p = __builtin_amdgcn_exp2f((sf[kc][r] - mnew) * L2E);
        ps += p;
        pw.h[r] = f2bf(p);
      }
      *(uint2*)&Ps[wave][l15][kc * 16 + lhi * 4] = pw.v;
    }
    ps += __shfl_xor(ps, 16, 64);
    ps += __shfl_xor(ps, 32, 64);
    l_acc = l_acc * scf + ps;

    // broadcast rescale factor to o_acc rows (o row = q = lhi*4+r)
    float scr[4];
#pragma unroll
    for (int r = 0; r < 4; r++) scr[r] = __shfl(scf, lhi * 4 + r, 64);
#pragma unroll
    for (int dc = 0; dc < 4; dc++)
#pragma unroll
      for (int r = 0; r < 4; r++) o_acc[dc][r] *= scr[r];

    // PV: A = P (from per-wave LDS), B = V^T rows (contiguous in key)
    bf16x8 pf0 = *(const bf16x8*)&Ps[wave][l15][lhi * 8];
    bf16x8 pf1 = *(const bf16x8*)&Ps[wave][l15][32 + lhi * 8];
#pragma unroll
    for (int dc = 0; dc < 4; dc++) {
      bf16x8 vf0 = *(const bf16x8*)&Vt[dc * 16 + l15][lhi * 8];
      bf16x8 vf1 = *(const bf16x8*)&Vt[dc * 16 + l15][32 + lhi * 8];
      o_acc[dc] = __builtin_amdgcn_mfma_f32_16x16x32_bf16(pf0, vf0, o_acc[dc], 0, 0, 0);
      o_acc[dc] = __builtin_amdgcn_mfma_f32_16x16x32_bf16(pf1, vf1, o_acc[dc], 0, 0, 0);
    }
    __syncthreads();
  }

  // epilogue: O /= l, write [b*T+t][h*64+d] bf16 (l lives at lane q=l15)
  float linv[4];
#pragma unroll
  for (int r = 0; r < 4; r++)
    linv[r] = 1.f / __shfl(l_acc, lhi * 4 + r, 64);
#pragma unroll
  for (int dc = 0; dc < 4; dc++) {
#pragma unroll
    for (int r = 0; r < 4; r++) {
      int t = q0 + wave * 16 + lhi * 4 + r;
      float o = o_acc[dc][r] * linv[r];
      yatt[((size_t)(b * SEQ + t)) * CEMB + h * DHEAD + dc * 16 + l15] = f2bf(o);
    }
  }
}

// ---------------- launch ----------------
extern "C" void kernel_launch(void* const* d_in, const int* in_sizes, int n_in,
                              void* d_out, int out_size, void* d_ws, size_t ws_size,
                              hipStream_t stream) {
  const float* x      = (const float*)d_in[0];
  const float* W_attn = (const float*)d_in[1];
  const float* b_attn = (const float*)d_in[2];
  const float* W_proj = (const float*)d_in[3];
  const float* b_proj = (const float*)d_in[4];
  float* out = (float*)d_out;

  u16* Xb   = (u16*)d_ws;                       // 8192*1024
  u16* Wab  = Xb  + (size_t)BTROWS * CEMB;      // 3072*1024
  u16* Wpb  = Wab + (size_t)3 * CEMB * CEMB;    // 1024*1024
  u16* QKV  = Wpb + (size_t)CEMB * CEMB;        // 8192*3072
  u16* Yatt = QKV + (size_t)BTROWS * 3 * CEMB;  // 8192*1024
  // total ws: 92.3 MB

  cvt_f32_bf16_kernel<<<2048, 256, 0, stream>>>(x, Xb, BTROWS * CEMB / 4);
  cvt_f32_bf16_kernel<<<1024, 256, 0, stream>>>(W_attn, Wab, 3 * CEMB * CEMB / 4);
  cvt_f32_bf16_kernel<<<512, 256, 0, stream>>>(W_proj, Wpb, CEMB * CEMB / 4);

  gemm_bt_kernel<true><<<dim3(3 * CEMB / 128, BTROWS / 128), 256, 0, stream>>>(
      Xb, Wab, b_attn, QKV, BTROWS, 3 * CEMB, CEMB);

  attn_kernel<<<dim3(SEQ / 64, NBATCH * NHEAD), 256, 0, stream>>>(QKV, Yatt);

  gemm_bt_kernel<false><<<dim3(CEMB / 128, BTROWS / 128), 256, 0, stream>>>(
      Yatt, Wpb, b_proj, out, BTROWS, CEMB, CEMB);
}

// Round 7
// 339.109 us; speedup vs baseline: 1.3375x; 1.1321x over previous
//
#include <hip/hip_runtime.h>
#include <stdint.h>

// CausalSelfAttention: B=4 T=2048 C=1024 H=16 D=64
// cast->bf16 | GEMM1 (QKV) | flash-attn (32x32 MFMA, in-reg P) | GEMM2

#define SEQ 2048
#define NBATCH 4
#define CEMB 1024
#define NHEAD 16
#define DHEAD 64
#define BTROWS (NBATCH * SEQ)  // 8192

typedef __bf16 bf16x8 __attribute__((ext_vector_type(8)));
typedef float f32x4 __attribute__((ext_vector_type(4)));
typedef float f32x16 __attribute__((ext_vector_type(16)));
typedef uint32_t u32x4 __attribute__((ext_vector_type(4)));
typedef unsigned short u16;

__device__ __forceinline__ u16 f2bf(float f) {
  union { float f; uint32_t u; } x; x.f = f;
  uint32_t u = x.u;
  return (u16)((u + 0x7FFFu + ((u >> 16) & 1u)) >> 16);  // RNE
}

// pack 2 f32 -> 2 bf16 in a u32 (compiler emits v_cvt_pk_bf16_f32)
__device__ __forceinline__ uint32_t pk2(float a, float b) {
  union { __bf16 h[2]; uint32_t u; } z;
  z.h[0] = (__bf16)a; z.h[1] = (__bf16)b;
  return z.u;
}

__device__ __forceinline__ void gload_lds16(const void* g, void* l) {
  __builtin_amdgcn_global_load_lds(
      (const __attribute__((address_space(1))) uint32_t*)g,
      (__attribute__((address_space(3))) uint32_t*)l, 16, 0, 0);
}

// ---------------- f32 -> bf16 cast ----------------
__global__ __launch_bounds__(256) void cvt_f32_bf16_kernel(
    const float* __restrict__ in, u16* __restrict__ out, int n4) {
  int i = blockIdx.x * blockDim.x + threadIdx.x;
  int stride = gridDim.x * blockDim.x;
  for (; i < n4; i += stride) {
    float4 v = reinterpret_cast<const float4*>(in)[i];
    ushort4 o;
    o.x = f2bf(v.x); o.y = f2bf(v.y); o.z = f2bf(v.z); o.w = f2bf(v.w);
    reinterpret_cast<ushort4*>(out)[i] = o;
  }
}

// ---------------- GEMM: C[M,N] = A[M,K] * Bt[N,K]^T + bias ----------------
template <bool OUT_BF16>
__global__ __launch_bounds__(256) void gemm_bt_kernel(
    const u16* __restrict__ A, const u16* __restrict__ Bt,
    const float* __restrict__ bias, void* __restrict__ Cout,
    int M, int N, int K) {
  __shared__ u16 As[128][64];
  __shared__ u16 Bs[128][64];
  const int tid = threadIdx.x;
  const int lane = tid & 63;
  const int wave = tid >> 6;
  const int wr = wave >> 1, wc = wave & 1;
  const int m0 = blockIdx.y * 128;
  const int n0 = blockIdx.x * 128;
  const int l15 = lane & 15, lhi = lane >> 4;

  f32x4 acc[4][4];
#pragma unroll
  for (int i = 0; i < 4; i++)
#pragma unroll
    for (int j = 0; j < 4; j++) acc[i][j] = (f32x4){0.f, 0.f, 0.f, 0.f};

  const int srow = lane >> 3;
  const int scol = (lane & 7) * 8;

  for (int kt = 0; kt < K; kt += 64) {
#pragma unroll
    for (int i = 0; i < 4; i++) {
      int rr = (wave * 4 + i) * 8 + srow;
      gload_lds16(A + (size_t)(m0 + rr) * K + kt + scol, &As[(wave * 4 + i) * 8][0]);
      gload_lds16(Bt + (size_t)(n0 + rr) * K + kt + scol, &Bs[(wave * 4 + i) * 8][0]);
    }
    __syncthreads();
#pragma unroll
    for (int ks = 0; ks < 2; ks++) {
      bf16x8 af[4], bfr[4];
#pragma unroll
      for (int mi = 0; mi < 4; mi++)
        af[mi] = *(const bf16x8*)&As[wr * 64 + mi * 16 + l15][ks * 32 + lhi * 8];
#pragma unroll
      for (int ni = 0; ni < 4; ni++)
        bfr[ni] = *(const bf16x8*)&Bs[wc * 64 + ni * 16 + l15][ks * 32 + lhi * 8];
#pragma unroll
      for (int mi = 0; mi < 4; mi++)
#pragma unroll
        for (int ni = 0; ni < 4; ni++)
          acc[mi][ni] = __builtin_amdgcn_mfma_f32_16x16x32_bf16(
              af[mi], bfr[ni], acc[mi][ni], 0, 0, 0);
    }
    __syncthreads();
  }

#pragma unroll
  for (int mi = 0; mi < 4; mi++) {
#pragma unroll
    for (int ni = 0; ni < 4; ni++) {
      int n = n0 + wc * 64 + ni * 16 + l15;
      float bv = bias[n];
#pragma unroll
      for (int r = 0; r < 4; r++) {
        int m = m0 + wr * 64 + mi * 16 + lhi * 4 + r;
        float v = acc[mi][ni][r] + bv;
        if constexpr (OUT_BF16)
          ((u16*)Cout)[(size_t)m * N + n] = f2bf(v);
        else
          ((float*)Cout)[(size_t)m * N + n] = v;
      }
    }
  }
}

// ---------------- flash attention (32x32 MFMA, QBLK=128, KVBLK=64) -------
// grid (16 qtiles, 64 bh), 256 thr = 4 waves x 32 q-rows.
// Swapped QK^T: St = mfma32(K, Q) -> lane owns q = lane&31; 32 chunk keys
// live in regs at key = kt*32 + (r&3)+8*(r>>2)+4*hi. Softmax fully in-reg:
// 1 shfl_xor(32) for max, 1 for sum. P->A-frag: 16 pk2 + 8 shfl_xor(32).
__global__ __launch_bounds__(256) void attn_kernel(
    const u16* __restrict__ qkv, u16* __restrict__ yatt) {
  __shared__ u16 Ks[64][64];  // K chunk, XOR-swizzled 16B blocks (8 KB)
  __shared__ u16 Vt[64][68];  // V^T chunk [d][key], pad 68 -> b64 reads 2-way (8.5 KB)

  const int tid = threadIdx.x;
  const int lane = tid & 63;
  const int wave = tid >> 6;
  const int qt = 15 - (int)blockIdx.x;  // heavy blocks first
  const int bh = blockIdx.y;
  const int b = bh >> 4, h = bh & 15;
  const int l31 = lane & 31, hi = lane >> 5;

  const size_t rs = 3 * CEMB;  // 3072
  const u16* qb = qkv + (size_t)b * SEQ * rs + h * DHEAD;
  const u16* kb = qb + CEMB;
  const u16* vb = qb + 2 * CEMB;

  const int q0 = qt * 128;
  const int qabs = q0 + wave * 32 + l31;  // this lane's q row

  // Q as B-operand: col=q=l31, k = dc*16 + hi*8 + j
  bf16x8 qf[4];
  {
    const u16* qp = qb + (size_t)qabs * rs + hi * 8;
#pragma unroll
    for (int dc = 0; dc < 4; dc++) qf[dc] = *(const bf16x8*)(qp + dc * 16);
  }

  float m_acc = -1e30f, l_acc = 0.f;  // state for q = l31 (mirrored in both halves)
  f32x16 o_acc[2];  // O[q=crow(r,hi)][d=dt*32+l31]
  o_acc[0] = (f32x16)(0.f);
  o_acc[1] = (f32x16)(0.f);

  const float SCLL2E = 0.125f * 1.44269504088896f;  // fold 1/sqrt(D) into exp2

  for (int s0 = 0; s0 <= q0 + 64; s0 += 64) {
    // ---- stage K via global_load_lds, pre-swizzled source ----
#pragma unroll
    for (int c = 0; c < 2; c++) {
      int row0 = (c * 4 + wave) * 8;
      int row = row0 + (lane >> 3);
      int cb = (lane & 7) ^ (row & 7);
      gload_lds16(kb + (size_t)(s0 + row) * rs + cb * 8, &Ks[row0][0]);
    }
    // ---- stage V transposed (lane=key -> 2-way free writes) ----
    {
      const u16* gv = vb + (size_t)(s0 + lane) * rs + wave * 16;
      union { u32x4 q[2]; u16 u[16]; } tv;
      tv.q[0] = *(const u32x4*)gv;
      tv.q[1] = *(const u32x4*)(gv + 8);
#pragma unroll
      for (int j = 0; j < 16; j++) Vt[wave * 16 + j][lane] = tv.u[j];
    }
    __syncthreads();

    const bool active = (s0 <= q0 + wave * 32 + 31);
    if (active) {
      // ---- St = K Q^T : sf[kt] C-frag, row=key, col=q ----
      f32x16 sf[2];
#pragma unroll
      for (int kt = 0; kt < 2; kt++) {
        f32x16 s = (f32x16)(0.f);
        int key = kt * 32 + l31;
#pragma unroll
        for (int dc = 0; dc < 4; dc++) {
          int cb = (dc * 2 + hi) ^ (key & 7);
          const bf16x8 kf = *(const bf16x8*)((const u16*)&Ks[key][0] + cb * 8);
          s = __builtin_amdgcn_mfma_f32_32x32x16_bf16(kf, qf[dc], s, 0, 0, 0);
        }
        sf[kt] = s;
      }

      // ---- causal mask (only near diagonal) ----
      if (s0 + 63 > q0 + wave * 32) {
#pragma unroll
        for (int kt = 0; kt < 2; kt++)
#pragma unroll
          for (int r = 0; r < 16; r++) {
            int key = s0 + kt * 32 + (r & 3) + 8 * (r >> 2) + 4 * hi;
            if (key > qabs) sf[kt][r] = -3e38f;
          }
      }

      // ---- row max (raw units) ----
      float cmax = sf[0][0];
#pragma unroll
      for (int r = 1; r < 16; r++) cmax = fmaxf(cmax, sf[0][r]);
#pragma unroll
      for (int r = 0; r < 16; r++) cmax = fmaxf(cmax, sf[1][r]);
      cmax = fmaxf(cmax, __shfl_xor(cmax, 32, 64));

      // ---- defer-max (T13): rescale only when max grew > 64 raw (=8 scaled) ----
      if (!__all(cmax <= m_acc + 64.0f)) {
        float mnew = fmaxf(m_acc, cmax);
        float scf = __builtin_amdgcn_exp2f((m_acc - mnew) * SCLL2E);
        m_acc = mnew;
        l_acc *= scf;
        float scr[16];
#pragma unroll
        for (int r = 0; r < 16; r++)
          scr[r] = __shfl(scf, (r & 3) + 8 * (r >> 2) + 4 * hi, 64);
#pragma unroll
        for (int r = 0; r < 16; r++) {
          o_acc[0][r] *= scr[r];
          o_acc[1][r] *= scr[r];
        }
      }

      // ---- P = exp2((s - m) * SCLL2E), row sum ----
      const float c1 = -m_acc * SCLL2E;
      float ps = 0.f;
#pragma unroll
      for (int kt = 0; kt < 2; kt++)
#pragma unroll
        for (int r = 0; r < 16; r++) {
          float p = __builtin_amdgcn_exp2f(fmaf(sf[kt][r], SCLL2E, c1));
          sf[kt][r] = p;
          ps += p;
        }
      ps += __shfl_xor(ps, 32, 64);
      l_acc += ps;

      // ---- P -> A-frag (in-register half-swap) ----
      // pa[ks] covers keys [ks*16, ks*16+16); lane needs keys ks*16+hi*8+(0..7)
      bf16x8 pa[4];
#pragma unroll
      for (int ks = 0; ks < 4; ks++) {
        const int t = ks >> 1;
        const int ra = (ks & 1) * 8;
        uint32_t a  = pk2(sf[t][ra + 0], sf[t][ra + 1]);  // keys ks*16+4hi+{0,1}
        uint32_t b2 = pk2(sf[t][ra + 2], sf[t][ra + 3]);  // +{2,3}
        uint32_t cc = pk2(sf[t][ra + 4], sf[t][ra + 5]);  // keys ks*16+8+4hi+{0,1}
        uint32_t dd = pk2(sf[t][ra + 6], sf[t][ra + 7]);  // +{2,3}
        uint32_t snd0 = hi ? a : cc;
        uint32_t snd1 = hi ? b2 : dd;
        uint32_t r0 = __shfl_xor(snd0, 32, 64);
        uint32_t r1 = __shfl_xor(snd1, 32, 64);
        union { bf16x8 v; uint32_t w[4]; } u;
        u.w[0] = hi ? r0 : a;
        u.w[1] = hi ? r1 : b2;
        u.w[2] = hi ? cc : r0;
        u.w[3] = hi ? dd : r1;
        pa[ks] = u.v;
      }

      // ---- PV: o_acc[dt] += P * V (B-frag from Vt, b64 reads) ----
#pragma unroll
      for (int dt = 0; dt < 2; dt++) {
        const u16* vrow = &Vt[dt * 32 + l31][hi * 8];
#pragma unroll
        for (int ks = 0; ks < 4; ks++) {
          union { bf16x8 v; uint2 d[2]; } u;
          u.d[0] = *(const uint2*)(vrow + ks * 16);
          u.d[1] = *(const uint2*)(vrow + ks * 16 + 4);
          o_acc[dt] = __builtin_amdgcn_mfma_f32_32x32x16_bf16(pa[ks], u.v, o_acc[dt], 0, 0, 0);
        }
      }
    }
    __syncthreads();
  }

  // ---- epilogue: O /= l, write bf16 ----
  float rl = 1.0f / l_acc;
#pragma unroll
  for (int r = 0; r < 16; r++) {
    int crow = (r & 3) + 8 * (r >> 2) + 4 * hi;
    float linv = __shfl(rl, crow, 64);
    int t = q0 + wave * 32 + crow;
    u16* yp = yatt + ((size_t)(b * SEQ + t)) * CEMB + h * DHEAD + l31;
    yp[0]  = f2bf(o_acc[0][r] * linv);
    yp[32] = f2bf(o_acc[1][r] * linv);
  }
}

// ---------------- launch ----------------
extern "C" void kernel_launch(void* const* d_in, const int* in_sizes, int n_in,
                              void* d_out, int out_size, void* d_ws, size_t ws_size,
                              hipStream_t stream) {
  const float* x      = (const float*)d_in[0];
  const float* W_attn = (const float*)d_in[1];
  const float* b_attn = (const float*)d_in[2];
  const float* W_proj = (const float*)d_in[3];
  const float* b_proj = (const float*)d_in[4];
  float* out = (float*)d_out;

  u16* Xb   = (u16*)d_ws;                       // 8192*1024
  u16* Wab  = Xb  + (size_t)BTROWS * CEMB;      // 3072*1024
  u16* Wpb  = Wab + (size_t)3 * CEMB * CEMB;    // 1024*1024
  u16* QKV  = Wpb + (size_t)CEMB * CEMB;        // 8192*3072
  u16* Yatt = QKV + (size_t)BTROWS * 3 * CEMB;  // 8192*1024

  cvt_f32_bf16_kernel<<<2048, 256, 0, stream>>>(x, Xb, BTROWS * CEMB / 4);
  cvt_f32_bf16_kernel<<<1024, 256, 0, stream>>>(W_attn, Wab, 3 * CEMB * CEMB / 4);
  cvt_f32_bf16_kernel<<<512, 256, 0, stream>>>(W_proj, Wpb, CEMB * CEMB / 4);

  gemm_bt_kernel<true><<<dim3(3 * CEMB / 128, BTROWS / 128), 256, 0, stream>>>(
      Xb, Wab, b_attn, QKV, BTROWS, 3 * CEMB, CEMB);

  attn_kernel<<<dim3(SEQ / 128, NBATCH * NHEAD), 256, 0, stream>>>(QKV, Yatt);

  gemm_bt_kernel<false><<<dim3(CEMB / 128, BTROWS / 128), 256, 0, stream>>>(
      Yatt, Wpb, b_proj, out, BTROWS, CEMB, CEMB);
}

// Round 8
// 331.082 us; speedup vs baseline: 1.3700x; 1.0242x over previous
//
#include <hip/hip_runtime.h>
#include <stdint.h>

// CausalSelfAttention: B=4 T=2048 C=1024 H=16 D=64
// cast->bf16 | GEMM1 (QKV) | flash-attn (32x32 MFMA, paired q-tiles, KVBLK=128) | GEMM2

#define SEQ 2048
#define NBATCH 4
#define CEMB 1024
#define NHEAD 16
#define DHEAD 64
#define BTROWS (NBATCH * SEQ)  // 8192

typedef __bf16 bf16x8 __attribute__((ext_vector_type(8)));
typedef float f32x4 __attribute__((ext_vector_type(4)));
typedef float f32x16 __attribute__((ext_vector_type(16)));
typedef uint32_t u32x4 __attribute__((ext_vector_type(4)));
typedef unsigned short u16;

__device__ __forceinline__ u16 f2bf(float f) {
  union { float f; uint32_t u; } x; x.f = f;
  uint32_t u = x.u;
  return (u16)((u + 0x7FFFu + ((u >> 16) & 1u)) >> 16);  // RNE
}

// pack 2 f32 -> 2 bf16 in a u32 (compiler emits v_cvt_pk_bf16_f32)
__device__ __forceinline__ uint32_t pk2(float a, float b) {
  union { __bf16 h[2]; uint32_t u; } z;
  z.h[0] = (__bf16)a; z.h[1] = (__bf16)b;
  return z.u;
}

__device__ __forceinline__ void gload_lds16(const void* g, void* l) {
  __builtin_amdgcn_global_load_lds(
      (const __attribute__((address_space(1))) uint32_t*)g,
      (__attribute__((address_space(3))) uint32_t*)l, 16, 0, 0);
}

// ---------------- f32 -> bf16 cast ----------------
__global__ __launch_bounds__(256) void cvt_f32_bf16_kernel(
    const float* __restrict__ in, u16* __restrict__ out, int n4) {
  int i = blockIdx.x * blockDim.x + threadIdx.x;
  int stride = gridDim.x * blockDim.x;
  for (; i < n4; i += stride) {
    float4 v = reinterpret_cast<const float4*>(in)[i];
    ushort4 o;
    o.x = f2bf(v.x); o.y = f2bf(v.y); o.z = f2bf(v.z); o.w = f2bf(v.w);
    reinterpret_cast<ushort4*>(out)[i] = o;
  }
}

// ---------------- GEMM: C[M,N] = A[M,K] * Bt[N,K]^T + bias ----------------
template <bool OUT_BF16>
__global__ __launch_bounds__(256) void gemm_bt_kernel(
    const u16* __restrict__ A, const u16* __restrict__ Bt,
    const float* __restrict__ bias, void* __restrict__ Cout,
    int M, int N, int K) {
  __shared__ u16 As[128][64];
  __shared__ u16 Bs[128][64];
  const int tid = threadIdx.x;
  const int lane = tid & 63;
  const int wave = tid >> 6;
  const int wr = wave >> 1, wc = wave & 1;
  const int m0 = blockIdx.y * 128;
  const int n0 = blockIdx.x * 128;
  const int l15 = lane & 15, lhi = lane >> 4;

  f32x4 acc[4][4];
#pragma unroll
  for (int i = 0; i < 4; i++)
#pragma unroll
    for (int j = 0; j < 4; j++) acc[i][j] = (f32x4){0.f, 0.f, 0.f, 0.f};

  const int srow = lane >> 3;
  const int scol = (lane & 7) * 8;

  for (int kt = 0; kt < K; kt += 64) {
#pragma unroll
    for (int i = 0; i < 4; i++) {
      int rr = (wave * 4 + i) * 8 + srow;
      gload_lds16(A + (size_t)(m0 + rr) * K + kt + scol, &As[(wave * 4 + i) * 8][0]);
      gload_lds16(Bt + (size_t)(n0 + rr) * K + kt + scol, &Bs[(wave * 4 + i) * 8][0]);
    }
    __syncthreads();
#pragma unroll
    for (int ks = 0; ks < 2; ks++) {
      bf16x8 af[4], bfr[4];
#pragma unroll
      for (int mi = 0; mi < 4; mi++)
        af[mi] = *(const bf16x8*)&As[wr * 64 + mi * 16 + l15][ks * 32 + lhi * 8];
#pragma unroll
      for (int ni = 0; ni < 4; ni++)
        bfr[ni] = *(const bf16x8*)&Bs[wc * 64 + ni * 16 + l15][ks * 32 + lhi * 8];
#pragma unroll
      for (int mi = 0; mi < 4; mi++)
#pragma unroll
        for (int ni = 0; ni < 4; ni++)
          acc[mi][ni] = __builtin_amdgcn_mfma_f32_16x16x32_bf16(
              af[mi], bfr[ni], acc[mi][ni], 0, 0, 0);
    }
    __syncthreads();
  }

#pragma unroll
  for (int mi = 0; mi < 4; mi++) {
#pragma unroll
    for (int ni = 0; ni < 4; ni++) {
      int n = n0 + wc * 64 + ni * 16 + l15;
      float bv = bias[n];
#pragma unroll
      for (int r = 0; r < 4; r++) {
        int m = m0 + wr * 64 + mi * 16 + lhi * 4 + r;
        float v = acc[mi][ni][r] + bv;
        if constexpr (OUT_BF16)
          ((u16*)Cout)[(size_t)m * N + n] = f2bf(v);
        else
          ((float*)Cout)[(size_t)m * N + n] = v;
      }
    }
  }
}

// ---------------- flash attention --------------------------------------
// QBLK=128 (4 waves x 32 q), KVBLK=128. grid (8 pairs, 64 bh): block p
// processes q-tiles {p, 15-p} -> (p+1)+(16-p)=17 chunks for EVERY block
// (uniform load, 512 blocks = exactly 2/CU). Swapped QK^T (32x32), fully
// in-reg softmax with tree reductions; mask only on the s0==q0 chunk.
__global__ __launch_bounds__(256) void attn_kernel(
    const u16* __restrict__ qkv, u16* __restrict__ yatt) {
  __shared__ u16 Ks[128][64];   // K chunk, XOR-swizzled 16B blocks (16 KB)
  __shared__ u16 Vt[64][132];   // V^T chunk [d][key], pad->stride 66 dw == 2 mod 32 (16.5 KB)

  const int tid = threadIdx.x;
  const int lane = tid & 63;
  const int wave = tid >> 6;
  const int p = blockIdx.x;   // 0..7
  const int bh = blockIdx.y;
  const int b = bh >> 4, h = bh & 15;
  const int l31 = lane & 31, hi = lane >> 5;

  const size_t rs = 3 * CEMB;  // 3072
  const u16* qb = qkv + (size_t)b * SEQ * rs + h * DHEAD;
  const u16* kb = qb + CEMB;
  const u16* vb = qb + 2 * CEMB;

  const float SCLL2E = 0.125f * 1.44269504088896f;  // 1/sqrt(D) folded into exp2

  for (int pass = 0; pass < 2; ++pass) {
    const int qt = pass ? (15 - p) : p;
    const int q0 = qt * 128;
    const int qabs = q0 + wave * 32 + l31;

    // Q as B-operand: col=q=l31, k = dc*16 + hi*8 + j
    bf16x8 qf[4];
    {
      const u16* qp = qb + (size_t)qabs * rs + hi * 8;
#pragma unroll
      for (int dc = 0; dc < 4; dc++) qf[dc] = *(const bf16x8*)(qp + dc * 16);
    }

    float m_acc = -1e30f, l_acc = 0.f;
    f32x16 o_acc[2];  // O[q=crow(r,hi)][d=dt*32+l31]
    o_acc[0] = (f32x16)(0.f);
    o_acc[1] = (f32x16)(0.f);

    for (int s0 = 0; s0 <= q0; s0 += 128) {
      // ---- stage K (128 rows) via global_load_lds, pre-swizzled source ----
#pragma unroll
      for (int c = 0; c < 4; c++) {
        int row0 = (c * 4 + wave) * 8;
        int row = row0 + (lane >> 3);
        int cb = (lane & 7) ^ (row & 7);
        gload_lds16(kb + (size_t)(s0 + row) * rs + cb * 8, &Ks[row0][0]);
      }
      // ---- stage V transposed (lane=key per half; row-contiguous writes) ----
#pragma unroll
      for (int half = 0; half < 2; ++half) {
        const u16* gv = vb + (size_t)(s0 + half * 64 + lane) * rs + wave * 16;
        union { u32x4 q[2]; u16 u[16]; } tv;
        tv.q[0] = *(const u32x4*)gv;
        tv.q[1] = *(const u32x4*)(gv + 8);
#pragma unroll
        for (int j = 0; j < 16; j++) Vt[wave * 16 + j][half * 64 + lane] = tv.u[j];
      }
      __syncthreads();

      // ---- St = K Q^T : sf[kt] C-frag, row=key=kt*32+l31, col=q ----
      f32x16 sf[4];
      __builtin_amdgcn_s_setprio(1);
#pragma unroll
      for (int kt = 0; kt < 4; kt++) {
        f32x16 s = (f32x16)(0.f);
        int key = kt * 32 + l31;
#pragma unroll
        for (int dc = 0; dc < 4; dc++) {
          int cb = (dc * 2 + hi) ^ (key & 7);
          const bf16x8 kf = *(const bf16x8*)((const u16*)&Ks[key][0] + cb * 8);
          s = __builtin_amdgcn_mfma_f32_32x32x16_bf16(kf, qf[dc], s, 0, 0, 0);
        }
        sf[kt] = s;
      }
      __builtin_amdgcn_s_setprio(0);

      // ---- causal mask: only the diagonal chunk ----
      if (s0 == q0) {
#pragma unroll
        for (int kt = 0; kt < 4; kt++)
#pragma unroll
          for (int r = 0; r < 16; r++) {
            int key = s0 + kt * 32 + (r & 3) + 8 * (r >> 2) + 4 * hi;
            if (key > qabs) sf[kt][r] = -3e38f;
          }
      }

      // ---- row max: tree (depth ~6), then 1 cross-half shfl ----
      float t16[16];
#pragma unroll
      for (int i = 0; i < 16; i++)
        t16[i] = fmaxf(fmaxf(sf[0][i], sf[1][i]), fmaxf(sf[2][i], sf[3][i]));
#pragma unroll
      for (int i = 0; i < 8; i++) t16[i] = fmaxf(t16[i], t16[i + 8]);
#pragma unroll
      for (int i = 0; i < 4; i++) t16[i] = fmaxf(t16[i], t16[i + 4]);
      float cmax = fmaxf(fmaxf(t16[0], t16[1]), fmaxf(t16[2], t16[3]));
      cmax = fmaxf(cmax, __shfl_xor(cmax, 32, 64));

      // ---- defer-max (T13): rescale only when max grew > 64 raw (=8 scaled) ----
      if (!__all(cmax <= m_acc + 64.0f)) {
        float mnew = fmaxf(m_acc, cmax);
        float scf = __builtin_amdgcn_exp2f((m_acc - mnew) * SCLL2E);
        m_acc = mnew;
        l_acc *= scf;
        float scr[16];
#pragma unroll
        for (int r = 0; r < 16; r++)
          scr[r] = __shfl(scf, (r & 3) + 8 * (r >> 2) + 4 * hi, 64);
#pragma unroll
        for (int r = 0; r < 16; r++) {
          o_acc[0][r] *= scr[r];
          o_acc[1][r] *= scr[r];
        }
      }

      // ---- P = exp2(s*SCLL2E - m*SCLL2E); tree sum ----
      const float c1 = -m_acc * SCLL2E;
#pragma unroll
      for (int kt = 0; kt < 4; kt++)
#pragma unroll
        for (int r = 0; r < 16; r++)
          sf[kt][r] = __builtin_amdgcn_exp2f(fmaf(sf[kt][r], SCLL2E, c1));
#pragma unroll
      for (int i = 0; i < 16; i++)
        t16[i] = (sf[0][i] + sf[1][i]) + (sf[2][i] + sf[3][i]);
#pragma unroll
      for (int i = 0; i < 8; i++) t16[i] = t16[i] + t16[i + 8];
#pragma unroll
      for (int i = 0; i < 4; i++) t16[i] = t16[i] + t16[i + 4];
      float ps = (t16[0] + t16[1]) + (t16[2] + t16[3]);
      ps += __shfl_xor(ps, 32, 64);
      l_acc += ps;

      // ---- P -> A-frag (in-register half-swap); pa[ks] = keys [ks*16, ks*16+16) ----
      bf16x8 pa[8];
#pragma unroll
      for (int ks = 0; ks < 8; ks++) {
        const int t = ks >> 1;
        const int ra = (ks & 1) * 8;
        uint32_t a  = pk2(sf[t][ra + 0], sf[t][ra + 1]);
        uint32_t b2 = pk2(sf[t][ra + 2], sf[t][ra + 3]);
        uint32_t cc = pk2(sf[t][ra + 4], sf[t][ra + 5]);
        uint32_t dd = pk2(sf[t][ra + 6], sf[t][ra + 7]);
        uint32_t snd0 = hi ? a : cc;
        uint32_t snd1 = hi ? b2 : dd;
        uint32_t r0 = __shfl_xor(snd0, 32, 64);
        uint32_t r1 = __shfl_xor(snd1, 32, 64);
        union { bf16x8 v; uint32_t w[4]; } u;
        u.w[0] = hi ? r0 : a;
        u.w[1] = hi ? r1 : b2;
        u.w[2] = hi ? cc : r0;
        u.w[3] = hi ? dd : r1;
        pa[ks] = u.v;
      }

      // ---- PV: o_acc[dt] += P * V ----
      __builtin_amdgcn_s_setprio(1);
#pragma unroll
      for (int dt = 0; dt < 2; dt++) {
        const u16* vrow = &Vt[dt * 32 + l31][hi * 8];
#pragma unroll
        for (int ks = 0; ks < 8; ks++) {
          union { bf16x8 v; uint2 d[2]; } u;
          u.d[0] = *(const uint2*)(vrow + ks * 16);
          u.d[1] = *(const uint2*)(vrow + ks * 16 + 4);
          o_acc[dt] = __builtin_amdgcn_mfma_f32_32x32x16_bf16(pa[ks], u.v, o_acc[dt], 0, 0, 0);
        }
      }
      __builtin_amdgcn_s_setprio(0);
      __syncthreads();
    }

    // ---- epilogue: O /= l, write bf16 ----
    float rl = 1.0f / l_acc;
#pragma unroll
    for (int r = 0; r < 16; r++) {
      int crow = (r & 3) + 8 * (r >> 2) + 4 * hi;
      float linv = __shfl(rl, crow, 64);
      int t = q0 + wave * 32 + crow;
      u16* yp = yatt + ((size_t)(b * SEQ + t)) * CEMB + h * DHEAD + l31;
      yp[0]  = f2bf(o_acc[0][r] * linv);
      yp[32] = f2bf(o_acc[1][r] * linv);
    }
  }
}

// ---------------- launch ----------------
extern "C" void kernel_launch(void* const* d_in, const int* in_sizes, int n_in,
                              void* d_out, int out_size, void* d_ws, size_t ws_size,
                              hipStream_t stream) {
  const float* x      = (const float*)d_in[0];
  const float* W_attn = (const float*)d_in[1];
  const float* b_attn = (const float*)d_in[2];
  const float* W_proj = (const float*)d_in[3];
  const float* b_proj = (const float*)d_in[4];
  float* out = (float*)d_out;

  u16* Xb   = (u16*)d_ws;                       // 8192*1024
  u16* Wab  = Xb  + (size_t)BTROWS * CEMB;      // 3072*1024
  u16* Wpb  = Wab + (size_t)3 * CEMB * CEMB;    // 1024*1024
  u16* QKV  = Wpb + (size_t)CEMB * CEMB;        // 8192*3072
  u16* Yatt = QKV + (size_t)BTROWS * 3 * CEMB;  // 8192*1024

  cvt_f32_bf16_kernel<<<2048, 256, 0, stream>>>(x, Xb, BTROWS * CEMB / 4);
  cvt_f32_bf16_kernel<<<1024, 256, 0, stream>>>(W_attn, Wab, 3 * CEMB * CEMB / 4);
  cvt_f32_bf16_kernel<<<512, 256, 0, stream>>>(W_proj, Wpb, CEMB * CEMB / 4);

  gemm_bt_kernel<true><<<dim3(3 * CEMB / 128, BTROWS / 128), 256, 0, stream>>>(
      Xb, Wab, b_attn, QKV, BTROWS, 3 * CEMB, CEMB);

  attn_kernel<<<dim3(8, NBATCH * NHEAD), 256, 0, stream>>>(QKV, Yatt);

  gemm_bt_kernel<false><<<dim3(CEMB / 128, BTROWS / 128), 256, 0, stream>>>(
      Yatt, Wpb, b_proj, out, BTROWS, CEMB, CEMB);
}